// Round 9
// baseline (523.323 us; speedup 1.0000x reference)
//
#include <hip/hip_runtime.h>
#include <hip/hip_bf16.h>

#define DEVI __device__ __forceinline__

using bf16x8 = __attribute__((ext_vector_type(8))) __bf16;
using f32x4  = __attribute__((ext_vector_type(4))) float;
using u16x8  = __attribute__((ext_vector_type(8))) unsigned short;

DEVI unsigned short f2bf(float f) {
  unsigned int u = __float_as_uint(f);
  u = (u + 0x7FFFu + ((u >> 16) & 1u)) >> 16;
  return (unsigned short)u;
}
DEVI float bf2f(unsigned short s) { return __uint_as_float(((unsigned int)s) << 16); }

// async global->LDS, 16B per lane; LDS dest must be wave-uniform-base + lane*16
DEVI void gld_lds16(const unsigned short* g, unsigned short* l) {
  __builtin_amdgcn_global_load_lds(
      (const __attribute__((address_space(1))) void*)g,
      (__attribute__((address_space(3))) void*)l, 16, 0, 0);
}

// ---------------- transpose + cast f32 -> bf16 : out[C][R] = in[R][C] ----------------
__global__ __launch_bounds__(256) void transpose_cast_kernel(const float* __restrict__ in,
                                                             unsigned short* __restrict__ out,
                                                             int R, int C) {
  __shared__ float tile[32][33];
  const int c0 = blockIdx.x * 32, r0 = blockIdx.y * 32;
  const int tx = threadIdx.x & 31, ty = threadIdx.x >> 5;
  for (int rr = ty; rr < 32; rr += 8)
    tile[rr][tx] = in[(size_t)(r0 + rr) * C + c0 + tx];
  __syncthreads();
  for (int cc = ty; cc < 32; cc += 8)
    out[(size_t)(c0 + cc) * R + r0 + tx] = f2bf(tile[tx][cc]);
}

// ---------------- cast v-weights, no transpose: Wv_nt[k][he] = bf16(w_qkv[k][2048+he])
__global__ __launch_bounds__(256) void castv_kernel(const float* __restrict__ w_qkv,
                                                    unsigned short* __restrict__ Wv_nt) {
  const int i = blockIdx.x * 256 + threadIdx.x;
  const int k = i >> 8, he4 = (i & 255) * 4;
  const float4 v = *(const float4*)&w_qkv[(size_t)k * 3072 + 2048 + he4];
  ushort4 o;
  o.x = f2bf(v.x); o.y = f2bf(v.y); o.z = f2bf(v.z); o.w = f2bf(v.w);
  *(ushort4*)&Wv_nt[(size_t)k * 1024 + he4] = o;
}

// ---------------- vectorized bf16 transpose: in[32768][1024] -> out[1024][32768] -----
__global__ __launch_bounds__(256) void transpose_bf16x4_kernel(const unsigned short* __restrict__ in,
                                                               unsigned short* __restrict__ out) {
  __shared__ unsigned short tile[64][68];
  const int r0 = blockIdx.x * 64;
  const int c0 = blockIdx.y * 64;
  const int t = threadIdx.x;
  const int tr = t >> 4, tc4 = (t & 15) * 4;
#pragma unroll
  for (int p = 0; p < 4; ++p) {
    const int rr = p * 16 + tr;
    *(ushort4*)&tile[rr][tc4] = *(const ushort4*)&in[(size_t)(r0 + rr) * 1024 + c0 + tc4];
  }
  __syncthreads();
#pragma unroll
  for (int p = 0; p < 4; ++p) {
    const int cc = p * 16 + tr;
    ushort4 o;
    o.x = tile[tc4 + 0][cc];
    o.y = tile[tc4 + 1][cc];
    o.z = tile[tc4 + 2][cc];
    o.w = tile[tc4 + 3][cc];
    *(ushort4*)&out[(size_t)(c0 + cc) * 32768 + r0 + tc4] = o;
  }
}

// ---------------- RMSNorm ------------------------------------------------------------
__global__ __launch_bounds__(256) void rmsnorm_kernel(const float* __restrict__ x,
                                                      const float* __restrict__ gamma,
                                                      unsigned short* __restrict__ xn) {
  __shared__ float wsum[4];
  const int row = blockIdx.x;
  const int t = threadIdx.x;
  const float4 v = *(const float4*)&x[(size_t)row * 1024 + t * 4];
  float s = v.x * v.x + v.y * v.y + v.z * v.z + v.w * v.w;
  for (int off = 32; off; off >>= 1) s += __shfl_down(s, off);
  if ((t & 63) == 0) wsum[t >> 6] = s;
  __syncthreads();
  const float tot = wsum[0] + wsum[1] + wsum[2] + wsum[3];
  const float scale = 32.0f / fmaxf(sqrtf(tot), 1e-12f);
  const float4 g = *(const float4*)&gamma[t * 4];
  ushort4 o;
  o.x = f2bf(v.x * scale * g.x);
  o.y = f2bf(v.y * scale * g.y);
  o.z = f2bf(v.z * scale * g.z);
  o.w = f2bf(v.w * scale * g.w);
  *(ushort4*)&xn[(size_t)row * 1024 + t * 4] = o;
}

// ---------------- Gram: Gp[z] = xnT_b[:, ksplit] @ xnT_b[:, ksplit]^T (lower tiles) --
__global__ __launch_bounds__(256) void gemm_gram_kernel(const unsigned short* __restrict__ xnT,
                                                        unsigned short* __restrict__ Gp) {
  if (blockIdx.x > blockIdx.y) return;
  __shared__ __align__(16) unsigned short Al[4096];
  __shared__ __align__(16) unsigned short Bl[4096];
  const int tid = threadIdx.x;
  const int lane = tid & 63, wid = tid >> 6;
  const int wr = wid >> 1, wc = wid & 1;
  const int r = lane & 15, kg = lane >> 4;
  const int rw0 = tid >> 2, q0 = (tid & 3) * 8;
  const size_t row0 = (size_t)blockIdx.y * 128, col0 = (size_t)blockIdx.x * 128;
  const int z = blockIdx.z;
  const size_t koff = (size_t)(z >> 2) * 8192 + (size_t)(z & 3) * 2048;
  f32x4 acc[4][4] = {};
  for (int k0 = 0; k0 < 2048; k0 += 32) {
    __syncthreads();
    gld_lds16(&xnT[(row0 + rw0) * 32768 + koff + k0 + q0], &Al[tid * 8]);
    gld_lds16(&xnT[(row0 + rw0 + 64) * 32768 + koff + k0 + q0], &Al[2048 + tid * 8]);
    gld_lds16(&xnT[(col0 + rw0) * 32768 + koff + k0 + q0], &Bl[tid * 8]);
    gld_lds16(&xnT[(col0 + rw0 + 64) * 32768 + koff + k0 + q0], &Bl[2048 + tid * 8]);
    __syncthreads();
    bf16x8 af[4], bfr[4];
#pragma unroll
    for (int m = 0; m < 4; ++m) af[m] = *(const bf16x8*)&Al[(wr * 64 + m * 16 + r) * 32 + kg * 8];
#pragma unroll
    for (int n = 0; n < 4; ++n) bfr[n] = *(const bf16x8*)&Bl[(wc * 64 + n * 16 + r) * 32 + kg * 8];
#pragma unroll
    for (int m = 0; m < 4; ++m)
#pragma unroll
      for (int n = 0; n < 4; ++n)
        acc[m][n] = __builtin_amdgcn_mfma_f32_16x16x32_bf16(af[m], bfr[n], acc[m][n], 0, 0, 0);
  }
  unsigned short* C = Gp + ((size_t)z << 20);
  const int rbase = wr * 64 + (lane >> 4) * 4;
  const int cbase = wc * 64 + (lane & 15);
#pragma unroll
  for (int m = 0; m < 4; ++m)
#pragma unroll
    for (int n = 0; n < 4; ++n)
#pragma unroll
      for (int j = 0; j < 4; ++j)
        C[(row0 + rbase + m * 16 + j) * 1024 + col0 + cbase + n * 16] = f2bf(acc[m][n][j]);
}

// ---------------- reduce split-K partials + mirror to full symmetric G (bf16) --------
__global__ __launch_bounds__(256) void greduce_kernel(const unsigned short* __restrict__ Gp,
                                                      unsigned short* __restrict__ G) {
  const int tj = blockIdx.x, ti = blockIdx.y, b = blockIdx.z;
  if ((tj >> 1) > (ti >> 1)) return;
  __shared__ float lds[64][65];
  const int t = threadIdx.x;
  const int r = t >> 2, c0 = (t & 3) * 16;
  const size_t idx = (size_t)(ti * 64 + r) * 1024 + tj * 64 + c0;
  float v[16];
#pragma unroll
  for (int j = 0; j < 16; ++j) v[j] = 0.f;
  for (int s = 0; s < 4; ++s) {
    const unsigned short* p = Gp + ((size_t)(b * 4 + s) << 20) + idx;
#pragma unroll
    for (int j = 0; j < 16; ++j) v[j] += bf2f(p[j]);
  }
  unsigned short* Gb = G + ((size_t)b << 20);
  __attribute__((aligned(16))) unsigned short buf[16];
#pragma unroll
  for (int j = 0; j < 16; ++j) buf[j] = f2bf(v[j]);
  { int4* dst = (int4*)&Gb[idx]; const int4* src = (const int4*)buf; dst[0] = src[0]; dst[1] = src[1]; }
  if ((ti >> 1) != (tj >> 1)) {
#pragma unroll
    for (int j = 0; j < 16; ++j) lds[r][c0 + j] = v[j];
    __syncthreads();
    const int x = t >> 2, y0 = (t & 3) * 16;
#pragma unroll
    for (int j = 0; j < 16; ++j) buf[j] = f2bf(lds[y0 + j][x]);
    int4* dst = (int4*)&Gb[(size_t)(tj * 64 + x) * 1024 + ti * 64 + y0];
    const int4* src = (const int4*)buf;
    dst[0] = src[0]; dst[1] = src[1];
  }
}

// ---------------- batched bf16 GEMM: C[M,N] = A @ Bt^T, bf16 out ---------------------
__global__ __launch_bounds__(256) void gemm_bt_batch_bf16(const unsigned short* __restrict__ A,
                                                          const unsigned short* __restrict__ Bt,
                                                          unsigned short* __restrict__ C,
                                                          int N, int K,
                                                          long long aStr, long long bStr, long long cStr) {
  __shared__ __align__(16) unsigned short Al[4096];
  __shared__ __align__(16) unsigned short Bl[4096];
  A += (size_t)blockIdx.z * aStr; Bt += (size_t)blockIdx.z * bStr; C += (size_t)blockIdx.z * cStr;
  const int tid = threadIdx.x;
  const int lane = tid & 63, wid = tid >> 6;
  const int wr = wid >> 1, wc = wid & 1;
  const int r = lane & 15, kg = lane >> 4;
  const int rw0 = tid >> 2, q0 = (tid & 3) * 8;
  const size_t row0 = (size_t)blockIdx.y * 128, col0 = (size_t)blockIdx.x * 128;
  f32x4 acc[4][4] = {};
  for (int k0 = 0; k0 < K; k0 += 32) {
    __syncthreads();
    gld_lds16(&A[(row0 + rw0) * K + k0 + q0], &Al[tid * 8]);
    gld_lds16(&A[(row0 + rw0 + 64) * K + k0 + q0], &Al[2048 + tid * 8]);
    gld_lds16(&Bt[(col0 + rw0) * K + k0 + q0], &Bl[tid * 8]);
    gld_lds16(&Bt[(col0 + rw0 + 64) * K + k0 + q0], &Bl[2048 + tid * 8]);
    __syncthreads();
    bf16x8 af[4], bfr[4];
#pragma unroll
    for (int m = 0; m < 4; ++m) af[m] = *(const bf16x8*)&Al[(wr * 64 + m * 16 + r) * 32 + kg * 8];
#pragma unroll
    for (int n = 0; n < 4; ++n) bfr[n] = *(const bf16x8*)&Bl[(wc * 64 + n * 16 + r) * 32 + kg * 8];
#pragma unroll
    for (int m = 0; m < 4; ++m)
#pragma unroll
      for (int n = 0; n < 4; ++n)
        acc[m][n] = __builtin_amdgcn_mfma_f32_16x16x32_bf16(af[m], bfr[n], acc[m][n], 0, 0, 0);
  }
  const int rbase = wr * 64 + (lane >> 4) * 4;
  const int cbase = wc * 64 + (lane & 15);
#pragma unroll
  for (int m = 0; m < 4; ++m)
#pragma unroll
    for (int n = 0; n < 4; ++n)
#pragma unroll
      for (int j = 0; j < 4; ++j)
        C[(row0 + rbase + m * 16 + j) * N + col0 + cbase + n * 16] = f2bf(acc[m][n][j]);
}

// ============== 256x256 slice-pipelined GEMM (T3+T4: 4-slot LDS ring, vmcnt(12)) =====
// K sliced into 32 x K32. Stage slice s+3 while computing slice s (3 slices in flight).
// LDS swizzle: logical k-group kg stored at phys = kg ^ (row&3) (conflict-free b128).
DEVI void stage_slice(const unsigned short* __restrict__ gA,
                      const unsigned short* __restrict__ gB,
                      unsigned short* lA, unsigned short* lB,
                      int s, int slot, int w, int lane) {
  const int ric = lane >> 2;                 // row within 16-row chunk
  const int phys = lane & 3;                 // physical 16B slot within row
  const int kg = phys ^ (ric & 3);           // logical k-group (pre-swizzled source)
#pragma unroll
  for (int i = 0; i < 2; ++i) {
    const int c = w * 2 + i;                 // chunk 0..15 (16 rows each)
    const int row = c * 16 + ric;            // 0..255
    const size_t goff = (size_t)row * 1024 + s * 32 + kg * 8;
    gld_lds16(gA + goff, lA + slot * 8192 + c * 512 + lane * 8);
    gld_lds16(gB + goff, lB + slot * 8192 + c * 512 + lane * 8);
  }
}

DEVI void compute_slice(const unsigned short* lA, const unsigned short* lB,
                        int slot, int wm, int wn, int lane, f32x4 (&acc)[8][4]) {
  const int r = lane & 15, kg = lane >> 4;
  const int sA = (kg ^ (r & 3)) * 8;         // swizzled read offset (ushorts)
  const unsigned short* pA = lA + slot * 8192 + (wm * 128 + r) * 32 + sA;
  const unsigned short* pB = lB + slot * 8192 + (wn * 64 + r) * 32 + sA;
  bf16x8 af[8], bfr[4];
#pragma unroll
  for (int m = 0; m < 8; ++m) af[m] = *(const bf16x8*)(pA + m * 512);
#pragma unroll
  for (int n = 0; n < 4; ++n) bfr[n] = *(const bf16x8*)(pB + n * 512);
  __builtin_amdgcn_s_setprio(1);
#pragma unroll
  for (int m = 0; m < 8; ++m)
#pragma unroll
    for (int n = 0; n < 4; ++n)
      acc[m][n] = __builtin_amdgcn_mfma_f32_16x16x32_bf16(af[m], bfr[n], acc[m][n], 0, 0, 0);
  __builtin_amdgcn_s_setprio(0);
}

#define VBAR()  asm volatile("s_barrier" ::: "memory")
#define VW12()  asm volatile("s_waitcnt vmcnt(12)" ::: "memory")
#define VW8()   asm volatile("s_waitcnt vmcnt(8)" ::: "memory")
#define VW4()   asm volatile("s_waitcnt vmcnt(4)" ::: "memory")
#define VW0()   asm volatile("s_waitcnt vmcnt(0)" ::: "memory")

__global__ __launch_bounds__(512, 2) void gemm_vout256_kernel(
    const unsigned short* __restrict__ A,       // xn [32768][1024]
    const unsigned short* __restrict__ BtV,     // v-weight rows [1024][1024]
    const unsigned short* __restrict__ WfoldT,  // [4][1024][1024]
    float* __restrict__ origv,
    float* __restrict__ outp) {
  __shared__ __align__(16) unsigned short lA[4 * 8192];   // 4 slots x 256rows x 32k
  __shared__ __align__(16) unsigned short lB[4 * 8192];
  const int tid = threadIdx.x;
  const int lane = tid & 63;
  const int w = tid >> 6;                 // 0..7
  const int wm = w >> 2, wn = w & 3;      // 2x4 wave grid
  const int cb = blockIdx.x & 7;          // col-tile: XCD-affine -> B L2-resident
  const int rb = blockIdx.x >> 3;         // row-tile 0..127
  const int b = rb >> 5;                  // batch
  const unsigned short* gA = A + (size_t)rb * 256 * 1024;
  const unsigned short* gB = (cb < 4)
      ? BtV + (size_t)cb * 256 * 1024
      : WfoldT + ((size_t)b << 20) + (size_t)(cb - 4) * 256 * 1024;

  f32x4 acc[8][4] = {};
  stage_slice(gA, gB, lA, lB, 0, 0, w, lane);
  stage_slice(gA, gB, lA, lB, 1, 1, w, lane);
  stage_slice(gA, gB, lA, lB, 2, 2, w, lane);
#pragma unroll 1
  for (int t4 = 0; t4 < 7; ++t4) {
    const int sb = t4 * 4;
#pragma unroll
    for (int j = 0; j < 4; ++j) {
      stage_slice(gA, gB, lA, lB, sb + j + 3, (j + 3) & 3, w, lane);
      VW12(); VBAR();
      compute_slice(lA, lB, j, wm, wn, lane, acc);
      VBAR();
    }
  }
  // tail slices 28..31
  stage_slice(gA, gB, lA, lB, 31, 3, w, lane);
  VW12(); VBAR(); compute_slice(lA, lB, 0, wm, wn, lane, acc); VBAR();
  VW8();  VBAR(); compute_slice(lA, lB, 1, wm, wn, lane, acc); VBAR();
  VW4();  VBAR(); compute_slice(lA, lB, 2, wm, wn, lane, acc); VBAR();
  VW0();  VBAR(); compute_slice(lA, lB, 3, wm, wn, lane, acc);

  const int rr = (lane >> 4) * 4;
  const int cc = lane & 15;
  if (cb < 4) {  // v panel -> origv[b][hd][n] f32 (float4 along n)
    const int nbase = (rb & 31) * 256 + wm * 128;
#pragma unroll
    for (int m = 0; m < 8; ++m)
#pragma unroll
      for (int n = 0; n < 4; ++n) {
        const int hd = cb * 256 + wn * 64 + n * 16 + cc;
        const float4 o4 = make_float4(acc[m][n][0], acc[m][n][1], acc[m][n][2], acc[m][n][3]);
        *(float4*)&origv[((size_t)b * 1024 + hd) * 8192 + nbase + m * 16 + rr] = o4;
      }
  } else {       // out panel -> outp row-major f32
    const size_t grow0 = (size_t)rb * 256 + wm * 128;
    const int gc0 = (cb - 4) * 256 + wn * 64;
#pragma unroll
    for (int m = 0; m < 8; ++m)
#pragma unroll
      for (int n = 0; n < 4; ++n)
#pragma unroll
        for (int j = 0; j < 4; ++j)
          outp[(grow0 + m * 16 + rr + j) * 1024 + gc0 + n * 16 + cc] = acc[m][n][j];
  }
}

// ---------------- norms: qkn2[b*2048+row] = dot(UTt_b[row], wqkvT[row]) --------------
__global__ __launch_bounds__(256) void norms_kernel(const unsigned short* __restrict__ UTt,
                                                    const unsigned short* __restrict__ wqkvT,
                                                    float* __restrict__ qkn2) {
  const int t = threadIdx.x;
  const int rloc = t >> 4, lane16 = t & 15;
  const int row = blockIdx.x * 16 + rloc;
  const int b = row >> 11, r2 = row & 2047;
  const unsigned short* pa = UTt + ((size_t)b << 21) + (size_t)r2 * 1024 + lane16 * 64;
  const unsigned short* pb = wqkvT + (size_t)r2 * 1024 + lane16 * 64;
  float s = 0.f;
  for (int i = 0; i < 64; i += 8) {
    const u16x8 va = *(const u16x8*)&pa[i];
    const u16x8 vb = *(const u16x8*)&pb[i];
#pragma unroll
    for (int j = 0; j < 8; ++j) s += bf2f(va[j]) * bf2f(vb[j]);
  }
  for (int off = 8; off; off >>= 1) s += __shfl_down(s, off, 16);
  if (lane16 == 0) qkn2[row] = s;
}

// ---------------- sim + softmax per (b,h): MFMA 64x64 over K=1024 --------------------
__global__ __launch_bounds__(256) void sim_softmax_kernel(const unsigned short* __restrict__ wqkvT,
                                                          const unsigned short* __restrict__ UTt,
                                                          const float* __restrict__ qkn2,
                                                          const float* __restrict__ temperature,
                                                          float* __restrict__ attn) {
  __shared__ __align__(16) unsigned short Aql[64 * 128];
  __shared__ __align__(16) unsigned short Bkl[64 * 128];
  __shared__ float qknl[2][64];
  const int bh = blockIdx.x;
  const int b = bh >> 4, h = bh & 15;
  const int t = threadIdx.x;
  const int lane = t & 63, w = t >> 6;
  const unsigned short* UTtb = UTt + ((size_t)b << 21);
  if (t < 128) {
    const int sel = t >> 6, dd = t & 63;
    qknl[sel][dd] = fmaxf(sqrtf(qkn2[b * 2048 + sel * 1024 + h * 64 + dd]), 1e-12f);
  }
  const unsigned short* AqG = UTtb + (size_t)(h * 64) * 1024;
  const unsigned short* BkG = wqkvT + (size_t)(1024 + h * 64) * 1024;
  const int r = lane & 15, kg = lane >> 4;
  const int srow = t >> 4, scol = (t & 15) * 8;
  f32x4 acc[4] = {};
  for (int k0 = 0; k0 < 1024; k0 += 128) {
    __syncthreads();
#pragma unroll
    for (int c = 0; c < 4; ++c) {
      gld_lds16(&AqG[(size_t)(c * 16 + srow) * 1024 + k0 + scol], &Aql[c * 2048 + t * 8]);
      gld_lds16(&BkG[(size_t)(c * 16 + srow) * 1024 + k0 + scol], &Bkl[c * 2048 + t * 8]);
    }
    __syncthreads();
#pragma unroll
    for (int kk = 0; kk < 128; kk += 32) {
      const bf16x8 af = *(const bf16x8*)&Aql[(w * 16 + r) * 128 + kk + kg * 8];
#pragma unroll
      for (int n = 0; n < 4; ++n) {
        const bf16x8 bfr = *(const bf16x8*)&Bkl[(n * 16 + r) * 128 + kk + kg * 8];
        acc[n] = __builtin_amdgcn_mfma_f32_16x16x32_bf16(af, bfr, acc[n], 0, 0, 0);
      }
    }
  }
  const float sc = 8.f * __expf(temperature[h]);
  const int colq = lane & 15, rq = lane >> 4;
#pragma unroll
  for (int j = 0; j < 4; ++j) {
    const int d = w * 16 + rq * 4 + j;
    const float qd = qknl[0][d];
    float sv[4];
#pragma unroll
    for (int n = 0; n < 4; ++n) sv[n] = acc[n][j] * sc / (qd * qknl[1][n * 16 + colq]);
    float mj = fmaxf(fmaxf(sv[0], sv[1]), fmaxf(sv[2], sv[3]));
    for (int msk = 1; msk < 16; msk <<= 1) mj = fmaxf(mj, __shfl_xor(mj, msk));
    float p[4], sum = 0.f;
#pragma unroll
    for (int n = 0; n < 4; ++n) { p[n] = __expf(sv[n] - mj); sum += p[n]; }
    for (int msk = 1; msk < 16; msk <<= 1) sum += __shfl_xor(sum, msk);
    const float inv = 1.f / sum;
#pragma unroll
    for (int n = 0; n < 4; ++n)
      attn[(size_t)bh * 4096 + d * 64 + n * 16 + colq] = p[n] * inv;
  }
}

// ---------------- W2T[b][c][h64+e] = sum_d attn[bh][d][e] * w_out[h64+d][c] ----------
__global__ __launch_bounds__(256) void w2t_kernel(const float* __restrict__ attn,
                                                  const float* __restrict__ w_out,
                                                  unsigned short* __restrict__ W2T) {
  __shared__ float al[64][64];
  __shared__ float wl[64][64];
  const int bh = blockIdx.y;
  const int b = bh >> 4, h = bh & 15;
  const int c0 = blockIdx.x * 256;
  const int t = threadIdx.x, e = t & 63, g = t >> 6;
  const int dr = t >> 2, q4 = (t & 3) * 16;
#pragma unroll
  for (int j = 0; j < 16; j += 4)
    *(float4*)&al[dr][q4 + j] = *(const float4*)&attn[(size_t)bh * 4096 + dr * 64 + q4 + j];
  for (int cbk = 0; cbk < 4; ++cbk) {
    __syncthreads();
#pragma unroll
    for (int j = 0; j < 16; j += 4)
      *(float4*)&wl[dr][q4 + j] = *(const float4*)&w_out[(size_t)(h * 64 + dr) * 1024 + c0 + cbk * 64 + q4 + j];
    __syncthreads();
#pragma unroll
    for (int i = 0; i < 16; ++i) {
      const int cc = g * 16 + i;
      float s = 0.f;
#pragma unroll 8
      for (int d = 0; d < 64; ++d) s += al[d][e] * wl[d][cc];
      W2T[((size_t)b << 20) + (size_t)(c0 + cbk * 64 + cc) * 1024 + h * 64 + e] = f2bf(s);
    }
  }
}

extern "C" void kernel_launch(void* const* d_in, const int* in_sizes, int n_in,
                              void* d_out, int out_size, void* d_ws, size_t ws_size,
                              hipStream_t stream) {
  const float* x     = (const float*)d_in[0];
  const float* gamma = (const float*)d_in[1];
  const float* w_qkv = (const float*)d_in[2];
  const float* temp  = (const float*)d_in[3];
  const float* w_out = (const float*)d_in[4];
  char* ws = (char*)d_ws;
  unsigned short* wqkvT  = (unsigned short*)(ws);                 // [3072][1024] bf16
  unsigned short* Wv_nt  = (unsigned short*)(ws + 6291456);       // [1024][1024] bf16
  unsigned short* xn     = (unsigned short*)(ws + 8388608);       // [32768][1024] bf16
  unsigned short* xnT    = (unsigned short*)(ws + 75497472);      // [1024][32768] bf16
  unsigned short* Gp     = (unsigned short*)(ws + 142606336);     // [16][1024][1024] bf16
  unsigned short* G      = (unsigned short*)(ws + 176160768);     // [4][1024][1024] bf16
  unsigned short* UTt    = (unsigned short*)(ws + 184549376);     // [4][2048][1024] bf16
  float* qkn2            = (float*)(ws + 201326592);              // [4][2048] f32
  float* attn            = (float*)(ws + 201359360);              // [64][64][64] f32
  unsigned short* W2T    = (unsigned short*)(ws + 202407936);     // [4][1024][1024] bf16
  unsigned short* WfoldT = (unsigned short*)(ws + 210796544);     // [4][1024][1024] bf16
  float* outp  = (float*)d_out;                                   // out: [4,8192,1024] f32
  float* origv = outp + (size_t)33554432;                         // orig_v: [4,16,64,8192] f32

  transpose_cast_kernel<<<dim3(96, 32), 256, 0, stream>>>(w_qkv, wqkvT, 1024, 3072);
  castv_kernel<<<1024, 256, 0, stream>>>(w_qkv, Wv_nt);
  rmsnorm_kernel<<<32768, 256, 0, stream>>>(x, gamma, xn);
  transpose_bf16x4_kernel<<<dim3(512, 16), 256, 0, stream>>>(xn, xnT);
  gemm_gram_kernel<<<dim3(8, 8, 16), 256, 0, stream>>>(xnT, Gp);
  greduce_kernel<<<dim3(16, 16, 4), 256, 0, stream>>>(Gp, G);
  gemm_bt_batch_bf16<<<dim3(8, 16, 4), 256, 0, stream>>>(wqkvT, G, UTt, 1024, 1024,
                                                         0LL, 1LL << 20, 1LL << 21);
  norms_kernel<<<512, 256, 0, stream>>>(UTt, wqkvT, qkn2);
  sim_softmax_kernel<<<64, 256, 0, stream>>>(wqkvT, UTt, qkn2, temp, attn);
  w2t_kernel<<<dim3(4, 64), 256, 0, stream>>>(attn, w_out, W2T);
  gemm_bt_batch_bf16<<<dim3(8, 8, 4), 256, 0, stream>>>(W2T, Wv_nt, WfoldT, 1024, 1024,
                                                        1LL << 20, 0LL, 1LL << 20);
  gemm_vout256_kernel<<<1024, 512, 0, stream>>>(xn, wqkvT + (size_t)2048 * 1024, WfoldT,
                                                origv, outp);
}

// Round 10
// 471.068 us; speedup vs baseline: 1.1109x; 1.1109x over previous
//
#include <hip/hip_runtime.h>
#include <hip/hip_bf16.h>

#define DEVI __device__ __forceinline__

using bf16x8 = __attribute__((ext_vector_type(8))) __bf16;
using f32x4  = __attribute__((ext_vector_type(4))) float;
using u16x8  = __attribute__((ext_vector_type(8))) unsigned short;

DEVI unsigned short f2bf(float f) {
  unsigned int u = __float_as_uint(f);
  u = (u + 0x7FFFu + ((u >> 16) & 1u)) >> 16;
  return (unsigned short)u;
}
DEVI float bf2f(unsigned short s) { return __uint_as_float(((unsigned int)s) << 16); }

// async global->LDS, 16B per lane; LDS dest must be wave-uniform-base + lane*16
DEVI void gld_lds16(const unsigned short* g, unsigned short* l) {
  __builtin_amdgcn_global_load_lds(
      (const __attribute__((address_space(1))) void*)g,
      (__attribute__((address_space(3))) void*)l, 16, 0, 0);
}

// ---------------- transpose + cast f32 -> bf16 : out[C][R] = in[R][C] ----------------
__global__ __launch_bounds__(256) void transpose_cast_kernel(const float* __restrict__ in,
                                                             unsigned short* __restrict__ out,
                                                             int R, int C) {
  __shared__ float tile[32][33];
  const int c0 = blockIdx.x * 32, r0 = blockIdx.y * 32;
  const int tx = threadIdx.x & 31, ty = threadIdx.x >> 5;
  for (int rr = ty; rr < 32; rr += 8)
    tile[rr][tx] = in[(size_t)(r0 + rr) * C + c0 + tx];
  __syncthreads();
  for (int cc = ty; cc < 32; cc += 8)
    out[(size_t)(c0 + cc) * R + r0 + tx] = f2bf(tile[tx][cc]);
}

// ---------------- cast v-weights, no transpose: Wv_nt[k][he] = bf16(w_qkv[k][2048+he])
__global__ __launch_bounds__(256) void castv_kernel(const float* __restrict__ w_qkv,
                                                    unsigned short* __restrict__ Wv_nt) {
  const int i = blockIdx.x * 256 + threadIdx.x;
  const int k = i >> 8, he4 = (i & 255) * 4;
  const float4 v = *(const float4*)&w_qkv[(size_t)k * 3072 + 2048 + he4];
  ushort4 o;
  o.x = f2bf(v.x); o.y = f2bf(v.y); o.z = f2bf(v.z); o.w = f2bf(v.w);
  *(ushort4*)&Wv_nt[(size_t)k * 1024 + he4] = o;
}

// ---------------- vectorized bf16 transpose: in[32768][1024] -> out[1024][32768] -----
__global__ __launch_bounds__(256) void transpose_bf16x4_kernel(const unsigned short* __restrict__ in,
                                                               unsigned short* __restrict__ out) {
  __shared__ unsigned short tile[64][68];
  const int r0 = blockIdx.x * 64;
  const int c0 = blockIdx.y * 64;
  const int t = threadIdx.x;
  const int tr = t >> 4, tc4 = (t & 15) * 4;
#pragma unroll
  for (int p = 0; p < 4; ++p) {
    const int rr = p * 16 + tr;
    *(ushort4*)&tile[rr][tc4] = *(const ushort4*)&in[(size_t)(r0 + rr) * 1024 + c0 + tc4];
  }
  __syncthreads();
#pragma unroll
  for (int p = 0; p < 4; ++p) {
    const int cc = p * 16 + tr;
    ushort4 o;
    o.x = tile[tc4 + 0][cc];
    o.y = tile[tc4 + 1][cc];
    o.z = tile[tc4 + 2][cc];
    o.w = tile[tc4 + 3][cc];
    *(ushort4*)&out[(size_t)(c0 + cc) * 32768 + r0 + tc4] = o;
  }
}

// ---------------- RMSNorm ------------------------------------------------------------
__global__ __launch_bounds__(256) void rmsnorm_kernel(const float* __restrict__ x,
                                                      const float* __restrict__ gamma,
                                                      unsigned short* __restrict__ xn) {
  __shared__ float wsum[4];
  const int row = blockIdx.x;
  const int t = threadIdx.x;
  const float4 v = *(const float4*)&x[(size_t)row * 1024 + t * 4];
  float s = v.x * v.x + v.y * v.y + v.z * v.z + v.w * v.w;
  for (int off = 32; off; off >>= 1) s += __shfl_down(s, off);
  if ((t & 63) == 0) wsum[t >> 6] = s;
  __syncthreads();
  const float tot = wsum[0] + wsum[1] + wsum[2] + wsum[3];
  const float scale = 32.0f / fmaxf(sqrtf(tot), 1e-12f);
  const float4 g = *(const float4*)&gamma[t * 4];
  ushort4 o;
  o.x = f2bf(v.x * scale * g.x);
  o.y = f2bf(v.y * scale * g.y);
  o.z = f2bf(v.z * scale * g.z);
  o.w = f2bf(v.w * scale * g.w);
  *(ushort4*)&xn[(size_t)row * 1024 + t * 4] = o;
}

// ============== shared 256x256 tile machinery (R8-verified: 0 bank conflicts) ========
// LDS rows of 64 ushorts (128 B); 16B slot s stored at s ^ (row&7); staged via
// pre-swizzled GLOBAL source + linear LDS dest (rule #21); reads apply same XOR.
DEVI void stage256(const unsigned short* __restrict__ gA,
                   const unsigned short* __restrict__ gB,
                   unsigned short* lA, unsigned short* lB,
                   int k0, int w, int lane, size_t gstride) {
  const int dr = lane >> 3;                 // row within octet
  const int ks = (lane & 7) ^ dr;           // pre-swizzled logical k-slot
  const size_t lo = (size_t)dr * gstride + k0 + ks * 8;
#pragma unroll
  for (int i = 0; i < 4; ++i) {
    const int oct = w * 4 + i;              // 8-row octet index (0..31)
    gld_lds16(gA + (size_t)oct * 8 * gstride + lo, lA + oct * 512 + lane * 8);
    gld_lds16(gB + (size_t)oct * 8 * gstride + lo, lB + oct * 512 + lane * 8);
  }
}

DEVI void compute256(const unsigned short* __restrict__ lA,
                     const unsigned short* __restrict__ lB,
                     int wm, int wn, int lane, f32x4 (&acc)[8][4]) {
  const int r = lane & 15, kg = lane >> 4;
  const int r7 = r & 7;
#pragma unroll
  for (int ksl = 0; ksl < 2; ++ksl) {
    const int sA = (((ksl << 2) + kg) ^ r7) * 8;   // swizzled 16B-slot, ushort offset
    bf16x8 af[8], bfr[4];
#pragma unroll
    for (int m = 0; m < 8; ++m)
      af[m] = *(const bf16x8*)&lA[(wm * 128 + m * 16 + r) * 64 + sA];
#pragma unroll
    for (int n = 0; n < 4; ++n)
      bfr[n] = *(const bf16x8*)&lB[(wn * 64 + n * 16 + r) * 64 + sA];
#pragma unroll
    for (int m = 0; m < 8; ++m)
#pragma unroll
      for (int n = 0; n < 4; ++n)
        acc[m][n] = __builtin_amdgcn_mfma_f32_16x16x32_bf16(af[m], bfr[n], acc[m][n], 0, 0, 0);
  }
}

#define VOUT_BAR()  __builtin_amdgcn_sched_barrier(0); __builtin_amdgcn_s_barrier(); \
                    __builtin_amdgcn_sched_barrier(0)
#define VOUT_W8()   asm volatile("s_waitcnt vmcnt(8)" ::: "memory")
#define VOUT_W0()   asm volatile("s_waitcnt vmcnt(0)" ::: "memory")

// ---------------- Gram 256²: Gp[z] = xnT_b[:,ksplit] @ xnT_b[:,ksplit]^T (lower) -----
__global__ __launch_bounds__(512, 2) void gemm_gram256_kernel(
    const unsigned short* __restrict__ xnT, unsigned short* __restrict__ Gp) {
  if (blockIdx.x > blockIdx.y) return;      // 256-tile lower triangle only
  __shared__ __align__(16) unsigned short Al[2][16384];
  __shared__ __align__(16) unsigned short Bl[2][16384];
  const int tid = threadIdx.x;
  const int lane = tid & 63;
  const int w = tid >> 6;
  const int wm = w >> 2, wn = w & 3;
  const int z = blockIdx.z;
  const size_t koff = (size_t)(z >> 2) * 8192 + (size_t)(z & 3) * 2048;
  const unsigned short* gA = xnT + (size_t)blockIdx.y * 256 * 32768 + koff;
  const unsigned short* gB = xnT + (size_t)blockIdx.x * 256 * 32768 + koff;

  f32x4 acc[8][4] = {};
  stage256(gA, gB, Al[0], Bl[0], 0, w, lane, 32768);        // tile 0 of 32
#pragma unroll 1
  for (int tt = 0; tt < 15; ++tt) {
    stage256(gA, gB, Al[1], Bl[1], (tt * 2 + 1) * 64, w, lane, 32768);
    VOUT_W8(); VOUT_BAR();
    __builtin_amdgcn_s_setprio(1);
    compute256(Al[0], Bl[0], wm, wn, lane, acc);
    __builtin_amdgcn_s_setprio(0);
    VOUT_BAR();
    stage256(gA, gB, Al[0], Bl[0], (tt * 2 + 2) * 64, w, lane, 32768);
    VOUT_W8(); VOUT_BAR();
    __builtin_amdgcn_s_setprio(1);
    compute256(Al[1], Bl[1], wm, wn, lane, acc);
    __builtin_amdgcn_s_setprio(0);
    VOUT_BAR();
  }
  stage256(gA, gB, Al[1], Bl[1], 31 * 64, w, lane, 32768);
  VOUT_W8(); VOUT_BAR();
  __builtin_amdgcn_s_setprio(1);
  compute256(Al[0], Bl[0], wm, wn, lane, acc);
  __builtin_amdgcn_s_setprio(0);
  VOUT_BAR();
  VOUT_W0(); VOUT_BAR();
  __builtin_amdgcn_s_setprio(1);
  compute256(Al[1], Bl[1], wm, wn, lane, acc);
  __builtin_amdgcn_s_setprio(0);

  unsigned short* C = Gp + ((size_t)z << 20);
  const int rr = (lane >> 4) * 4;
  const int cc = lane & 15;
  const size_t grow0 = (size_t)blockIdx.y * 256 + wm * 128;
  const int gc0 = blockIdx.x * 256 + wn * 64;
#pragma unroll
  for (int m = 0; m < 8; ++m)
#pragma unroll
    for (int n = 0; n < 4; ++n)
#pragma unroll
      for (int j = 0; j < 4; ++j)
        C[(grow0 + m * 16 + rr + j) * 1024 + gc0 + n * 16 + cc] = f2bf(acc[m][n][j]);
}

// ---------------- reduce split-K partials + mirror to full symmetric G (bf16) --------
// computed region is now 256-tile lower triangle -> granularity >>2 on 64-tiles
__global__ __launch_bounds__(256) void greduce_kernel(const unsigned short* __restrict__ Gp,
                                                      unsigned short* __restrict__ G) {
  const int tj = blockIdx.x, ti = blockIdx.y, b = blockIdx.z;
  if ((tj >> 2) > (ti >> 2)) return;
  __shared__ float lds[64][65];
  const int t = threadIdx.x;
  const int r = t >> 2, c0 = (t & 3) * 16;
  const size_t idx = (size_t)(ti * 64 + r) * 1024 + tj * 64 + c0;
  float v[16];
#pragma unroll
  for (int j = 0; j < 16; ++j) v[j] = 0.f;
  for (int s = 0; s < 4; ++s) {
    const unsigned short* p = Gp + ((size_t)(b * 4 + s) << 20) + idx;
#pragma unroll
    for (int j = 0; j < 16; ++j) v[j] += bf2f(p[j]);
  }
  unsigned short* Gb = G + ((size_t)b << 20);
  __attribute__((aligned(16))) unsigned short buf[16];
#pragma unroll
  for (int j = 0; j < 16; ++j) buf[j] = f2bf(v[j]);
  { int4* dst = (int4*)&Gb[idx]; const int4* src = (const int4*)buf; dst[0] = src[0]; dst[1] = src[1]; }
  if ((ti >> 2) != (tj >> 2)) {   // mirror to upper region
#pragma unroll
    for (int j = 0; j < 16; ++j) lds[r][c0 + j] = v[j];
    __syncthreads();
    const int x = t >> 2, y0 = (t & 3) * 16;
#pragma unroll
    for (int j = 0; j < 16; ++j) buf[j] = f2bf(lds[y0 + j][x]);
    int4* dst = (int4*)&Gb[(size_t)(tj * 64 + x) * 1024 + ti * 64 + y0];
    const int4* src = (const int4*)buf;
    dst[0] = src[0]; dst[1] = src[1];
  }
}

// ---------------- batched bf16 GEMM: C[M,N] = A @ Bt^T, bf16 out ---------------------
__global__ __launch_bounds__(256) void gemm_bt_batch_bf16(const unsigned short* __restrict__ A,
                                                          const unsigned short* __restrict__ Bt,
                                                          unsigned short* __restrict__ C,
                                                          int N, int K,
                                                          long long aStr, long long bStr, long long cStr) {
  __shared__ __align__(16) unsigned short Al[4096];
  __shared__ __align__(16) unsigned short Bl[4096];
  A += (size_t)blockIdx.z * aStr; Bt += (size_t)blockIdx.z * bStr; C += (size_t)blockIdx.z * cStr;
  const int tid = threadIdx.x;
  const int lane = tid & 63, wid = tid >> 6;
  const int wr = wid >> 1, wc = wid & 1;
  const int r = lane & 15, kg = lane >> 4;
  const int rw0 = tid >> 2, q0 = (tid & 3) * 8;
  const size_t row0 = (size_t)blockIdx.y * 128, col0 = (size_t)blockIdx.x * 128;
  f32x4 acc[4][4] = {};
  for (int k0 = 0; k0 < K; k0 += 32) {
    __syncthreads();
    gld_lds16(&A[(row0 + rw0) * K + k0 + q0], &Al[tid * 8]);
    gld_lds16(&A[(row0 + rw0 + 64) * K + k0 + q0], &Al[2048 + tid * 8]);
    gld_lds16(&Bt[(col0 + rw0) * K + k0 + q0], &Bl[tid * 8]);
    gld_lds16(&Bt[(col0 + rw0 + 64) * K + k0 + q0], &Bl[2048 + tid * 8]);
    __syncthreads();
    bf16x8 af[4], bfr[4];
#pragma unroll
    for (int m = 0; m < 4; ++m) af[m] = *(const bf16x8*)&Al[(wr * 64 + m * 16 + r) * 32 + kg * 8];
#pragma unroll
    for (int n = 0; n < 4; ++n) bfr[n] = *(const bf16x8*)&Bl[(wc * 64 + n * 16 + r) * 32 + kg * 8];
#pragma unroll
    for (int m = 0; m < 4; ++m)
#pragma unroll
      for (int n = 0; n < 4; ++n)
        acc[m][n] = __builtin_amdgcn_mfma_f32_16x16x32_bf16(af[m], bfr[n], acc[m][n], 0, 0, 0);
  }
  const int rbase = wr * 64 + (lane >> 4) * 4;
  const int cbase = wc * 64 + (lane & 15);
#pragma unroll
  for (int m = 0; m < 4; ++m)
#pragma unroll
    for (int n = 0; n < 4; ++n)
#pragma unroll
      for (int j = 0; j < 4; ++j)
        C[(row0 + rbase + m * 16 + j) * N + col0 + cbase + n * 16] = f2bf(acc[m][n][j]);
}

// ============== 256x256 dbuf vout GEMM (R8-verified: 209us, 0 conflicts) =============
__global__ __launch_bounds__(512, 2) void gemm_vout256_kernel(
    const unsigned short* __restrict__ A,       // xn [32768][1024]
    const unsigned short* __restrict__ BtV,     // v-weight rows [1024][1024]
    const unsigned short* __restrict__ WfoldT,  // [4][1024][1024]
    float* __restrict__ origv,
    float* __restrict__ outp) {
  __shared__ __align__(16) unsigned short Al[2][16384];
  __shared__ __align__(16) unsigned short Bl[2][16384];
  const int tid = threadIdx.x;
  const int lane = tid & 63;
  const int w = tid >> 6;                 // 0..7
  const int wm = w >> 2, wn = w & 3;      // 2x4 wave grid
  const int cb = blockIdx.x & 7;          // col-tile: XCD-affine -> B L2-resident
  const int rb = blockIdx.x >> 3;         // row-tile 0..127
  const int b = rb >> 5;                  // batch
  const unsigned short* gA = A + (size_t)rb * 256 * 1024;
  const unsigned short* gB = (cb < 4)
      ? BtV + (size_t)cb * 256 * 1024
      : WfoldT + ((size_t)b << 20) + (size_t)(cb - 4) * 256 * 1024;

  f32x4 acc[8][4] = {};
  stage256(gA, gB, Al[0], Bl[0], 0, w, lane, 1024);         // tile 0
#pragma unroll 1
  for (int tt = 0; tt < 7; ++tt) {                          // tiles 2tt, 2tt+1
    stage256(gA, gB, Al[1], Bl[1], (tt * 2 + 1) * 64, w, lane, 1024);
    VOUT_W8(); VOUT_BAR();
    __builtin_amdgcn_s_setprio(1);
    compute256(Al[0], Bl[0], wm, wn, lane, acc);
    __builtin_amdgcn_s_setprio(0);
    VOUT_BAR();
    stage256(gA, gB, Al[0], Bl[0], (tt * 2 + 2) * 64, w, lane, 1024);
    VOUT_W8(); VOUT_BAR();
    __builtin_amdgcn_s_setprio(1);
    compute256(Al[1], Bl[1], wm, wn, lane, acc);
    __builtin_amdgcn_s_setprio(0);
    VOUT_BAR();
  }
  // tiles 14, 15
  stage256(gA, gB, Al[1], Bl[1], 15 * 64, w, lane, 1024);
  VOUT_W8(); VOUT_BAR();
  __builtin_amdgcn_s_setprio(1);
  compute256(Al[0], Bl[0], wm, wn, lane, acc);
  __builtin_amdgcn_s_setprio(0);
  VOUT_BAR();
  VOUT_W0(); VOUT_BAR();
  __builtin_amdgcn_s_setprio(1);
  compute256(Al[1], Bl[1], wm, wn, lane, acc);
  __builtin_amdgcn_s_setprio(0);

  const int rr = (lane >> 4) * 4;
  const int cc = lane & 15;
  if (cb < 4) {  // v panel -> origv[b][hd][n] f32 (float4 along n)
    const int nbase = (rb & 31) * 256 + wm * 128;
#pragma unroll
    for (int m = 0; m < 8; ++m)
#pragma unroll
      for (int n = 0; n < 4; ++n) {
        const int hd = cb * 256 + wn * 64 + n * 16 + cc;
        const float4 o4 = make_float4(acc[m][n][0], acc[m][n][1], acc[m][n][2], acc[m][n][3]);
        *(float4*)&origv[((size_t)b * 1024 + hd) * 8192 + nbase + m * 16 + rr] = o4;
      }
  } else {       // out panel -> outp row-major f32
    const size_t grow0 = (size_t)rb * 256 + wm * 128;
    const int gc0 = (cb - 4) * 256 + wn * 64;
#pragma unroll
    for (int m = 0; m < 8; ++m)
#pragma unroll
      for (int n = 0; n < 4; ++n)
#pragma unroll
        for (int j = 0; j < 4; ++j)
          outp[(grow0 + m * 16 + rr + j) * 1024 + gc0 + n * 16 + cc] = acc[m][n][j];
  }
}

// ---------------- norms: qkn2[b*2048+row] = dot(UTt_b[row], wqkvT[row]) --------------
__global__ __launch_bounds__(256) void norms_kernel(const unsigned short* __restrict__ UTt,
                                                    const unsigned short* __restrict__ wqkvT,
                                                    float* __restrict__ qkn2) {
  const int t = threadIdx.x;
  const int rloc = t >> 4, lane16 = t & 15;
  const int row = blockIdx.x * 16 + rloc;
  const int b = row >> 11, r2 = row & 2047;
  const unsigned short* pa = UTt + ((size_t)b << 21) + (size_t)r2 * 1024 + lane16 * 64;
  const unsigned short* pb = wqkvT + (size_t)r2 * 1024 + lane16 * 64;
  float s = 0.f;
  for (int i = 0; i < 64; i += 8) {
    const u16x8 va = *(const u16x8*)&pa[i];
    const u16x8 vb = *(const u16x8*)&pb[i];
#pragma unroll
    for (int j = 0; j < 8; ++j) s += bf2f(va[j]) * bf2f(vb[j]);
  }
  for (int off = 8; off; off >>= 1) s += __shfl_down(s, off, 16);
  if (lane16 == 0) qkn2[row] = s;
}

// ---------------- sim + softmax per (b,h): MFMA 64x64 over K=1024 --------------------
__global__ __launch_bounds__(256) void sim_softmax_kernel(const unsigned short* __restrict__ wqkvT,
                                                          const unsigned short* __restrict__ UTt,
                                                          const float* __restrict__ qkn2,
                                                          const float* __restrict__ temperature,
                                                          float* __restrict__ attn) {
  __shared__ __align__(16) unsigned short Aql[64 * 128];
  __shared__ __align__(16) unsigned short Bkl[64 * 128];
  __shared__ float qknl[2][64];
  const int bh = blockIdx.x;
  const int b = bh >> 4, h = bh & 15;
  const int t = threadIdx.x;
  const int lane = t & 63, w = t >> 6;
  const unsigned short* UTtb = UTt + ((size_t)b << 21);
  if (t < 128) {
    const int sel = t >> 6, dd = t & 63;
    qknl[sel][dd] = fmaxf(sqrtf(qkn2[b * 2048 + sel * 1024 + h * 64 + dd]), 1e-12f);
  }
  const unsigned short* AqG = UTtb + (size_t)(h * 64) * 1024;
  const unsigned short* BkG = wqkvT + (size_t)(1024 + h * 64) * 1024;
  const int r = lane & 15, kg = lane >> 4;
  const int srow = t >> 4, scol = (t & 15) * 8;
  f32x4 acc[4] = {};
  for (int k0 = 0; k0 < 1024; k0 += 128) {
    __syncthreads();
#pragma unroll
    for (int c = 0; c < 4; ++c) {
      gld_lds16(&AqG[(size_t)(c * 16 + srow) * 1024 + k0 + scol], &Aql[c * 2048 + t * 8]);
      gld_lds16(&BkG[(size_t)(c * 16 + srow) * 1024 + k0 + scol], &Bkl[c * 2048 + t * 8]);
    }
    __syncthreads();
#pragma unroll
    for (int kk = 0; kk < 128; kk += 32) {
      const bf16x8 af = *(const bf16x8*)&Aql[(w * 16 + r) * 128 + kk + kg * 8];
#pragma unroll
      for (int n = 0; n < 4; ++n) {
        const bf16x8 bfr = *(const bf16x8*)&Bkl[(n * 16 + r) * 128 + kk + kg * 8];
        acc[n] = __builtin_amdgcn_mfma_f32_16x16x32_bf16(af, bfr, acc[n], 0, 0, 0);
      }
    }
  }
  const float sc = 8.f * __expf(temperature[h]);
  const int colq = lane & 15, rq = lane >> 4;
#pragma unroll
  for (int j = 0; j < 4; ++j) {
    const int d = w * 16 + rq * 4 + j;
    const float qd = qknl[0][d];
    float sv[4];
#pragma unroll
    for (int n = 0; n < 4; ++n) sv[n] = acc[n][j] * sc / (qd * qknl[1][n * 16 + colq]);
    float mj = fmaxf(fmaxf(sv[0], sv[1]), fmaxf(sv[2], sv[3]));
    for (int msk = 1; msk < 16; msk <<= 1) mj = fmaxf(mj, __shfl_xor(mj, msk));
    float p[4], sum = 0.f;
#pragma unroll
    for (int n = 0; n < 4; ++n) { p[n] = __expf(sv[n] - mj); sum += p[n]; }
    for (int msk = 1; msk < 16; msk <<= 1) sum += __shfl_xor(sum, msk);
    const float inv = 1.f / sum;
#pragma unroll
    for (int n = 0; n < 4; ++n)
      attn[(size_t)bh * 4096 + d * 64 + n * 16 + colq] = p[n] * inv;
  }
}

// ---------------- W2T[b][c][h64+e] = sum_d attn[bh][d][e] * w_out[h64+d][c] ----------
__global__ __launch_bounds__(256) void w2t_kernel(const float* __restrict__ attn,
                                                  const float* __restrict__ w_out,
                                                  unsigned short* __restrict__ W2T) {
  __shared__ float al[64][64];
  __shared__ float wl[64][64];
  const int bh = blockIdx.y;
  const int b = bh >> 4, h = bh & 15;
  const int c0 = blockIdx.x * 256;
  const int t = threadIdx.x, e = t & 63, g = t >> 6;
  const int dr = t >> 2, q4 = (t & 3) * 16;
#pragma unroll
  for (int j = 0; j < 16; j += 4)
    *(float4*)&al[dr][q4 + j] = *(const float4*)&attn[(size_t)bh * 4096 + dr * 64 + q4 + j];
  for (int cbk = 0; cbk < 4; ++cbk) {
    __syncthreads();
#pragma unroll
    for (int j = 0; j < 16; j += 4)
      *(float4*)&wl[dr][q4 + j] = *(const float4*)&w_out[(size_t)(h * 64 + dr) * 1024 + c0 + cbk * 64 + q4 + j];
    __syncthreads();
#pragma unroll
    for (int i = 0; i < 16; ++i) {
      const int cc = g * 16 + i;
      float s = 0.f;
#pragma unroll 8
      for (int d = 0; d < 64; ++d) s += al[d][e] * wl[d][cc];
      W2T[((size_t)b << 20) + (size_t)(c0 + cbk * 64 + cc) * 1024 + h * 64 + e] = f2bf(s);
    }
  }
}

extern "C" void kernel_launch(void* const* d_in, const int* in_sizes, int n_in,
                              void* d_out, int out_size, void* d_ws, size_t ws_size,
                              hipStream_t stream) {
  const float* x     = (const float*)d_in[0];
  const float* gamma = (const float*)d_in[1];
  const float* w_qkv = (const float*)d_in[2];
  const float* temp  = (const float*)d_in[3];
  const float* w_out = (const float*)d_in[4];
  char* ws = (char*)d_ws;
  unsigned short* wqkvT  = (unsigned short*)(ws);                 // [3072][1024] bf16
  unsigned short* Wv_nt  = (unsigned short*)(ws + 6291456);       // [1024][1024] bf16
  unsigned short* xn     = (unsigned short*)(ws + 8388608);       // [32768][1024] bf16
  unsigned short* xnT    = (unsigned short*)(ws + 75497472);      // [1024][32768] bf16
  unsigned short* Gp     = (unsigned short*)(ws + 142606336);     // [16][1024][1024] bf16
  unsigned short* G      = (unsigned short*)(ws + 176160768);     // [4][1024][1024] bf16
  unsigned short* UTt    = (unsigned short*)(ws + 184549376);     // [4][2048][1024] bf16
  float* qkn2            = (float*)(ws + 201326592);              // [4][2048] f32
  float* attn            = (float*)(ws + 201359360);              // [64][64][64] f32
  unsigned short* W2T    = (unsigned short*)(ws + 202407936);     // [4][1024][1024] bf16
  unsigned short* WfoldT = (unsigned short*)(ws + 210796544);     // [4][1024][1024] bf16
  float* outp  = (float*)d_out;                                   // out: [4,8192,1024] f32
  float* origv = outp + (size_t)33554432;                         // orig_v: [4,16,64,8192] f32

  transpose_cast_kernel<<<dim3(96, 32), 256, 0, stream>>>(w_qkv, wqkvT, 1024, 3072);
  castv_kernel<<<1024, 256, 0, stream>>>(w_qkv, Wv_nt);
  rmsnorm_kernel<<<32768, 256, 0, stream>>>(x, gamma, xn);
  transpose_bf16x4_kernel<<<dim3(512, 16), 256, 0, stream>>>(xn, xnT);
  gemm_gram256_kernel<<<dim3(4, 4, 16), 512, 0, stream>>>(xnT, Gp);
  greduce_kernel<<<dim3(16, 16, 4), 256, 0, stream>>>(Gp, G);
  gemm_bt_batch_bf16<<<dim3(8, 16, 4), 256, 0, stream>>>(wqkvT, G, UTt, 1024, 1024,
                                                         0LL, 1LL << 20, 1LL << 21);
  norms_kernel<<<512, 256, 0, stream>>>(UTt, wqkvT, qkn2);
  sim_softmax_kernel<<<64, 256, 0, stream>>>(wqkvT, UTt, qkn2, temp, attn);
  w2t_kernel<<<dim3(4, 64), 256, 0, stream>>>(attn, w_out, W2T);
  gemm_bt_batch_bf16<<<dim3(8, 8, 4), 256, 0, stream>>>(W2T, Wv_nt, WfoldT, 1024, 1024,
                                                        1LL << 20, 0LL, 1LL << 20);
  gemm_vout256_kernel<<<1024, 512, 0, stream>>>(xn, wqkvT + (size_t)2048 * 1024, WfoldT,
                                                origv, outp);
}